// Round 5
// baseline (700.503 us; speedup 1.0000x reference)
//
#include <hip/hip_runtime.h>
#include <hip/hip_bf16.h>

#define NUM_ENT   30000
#define NUM_ATTR  10000
#define NUM_TYPES 10
#define HIDDEN    200
#define KPAD      224      // HIDDEN padded to 7*32 for MFMA K-tiles
#define NPAD      30080    // NUM_ENT padded to 235*128
#define N_EDGES   600000
#define BATCH     4096
#define XDIM      401      // 2*HIDDEN + 1
#define RRELU_SLOPE 0.22916666666666666f

using bf16x8 = __attribute__((ext_vector_type(8))) short;
using f32x4  = __attribute__((ext_vector_type(4))) float;
typedef __hip_bfloat16 bf16;

// ---------------------------------------------------------------------------
// Zero an int array (histogram counters).
// ---------------------------------------------------------------------------
__global__ void k_zero_i(int* __restrict__ p, int n) {
    int i = blockIdx.x * blockDim.x + threadIdx.x;
    if (i < n) p[i] = 0;
}

// ---------------------------------------------------------------------------
// Histogram of edge destinations (dst < NUM_ENT only).
// ---------------------------------------------------------------------------
__global__ void k_hist(const int* __restrict__ edst, int* __restrict__ counts) {
    int e = blockIdx.x * blockDim.x + threadIdx.x;
    if (e < N_EDGES) {
        int d = edst[e];
        if (d < NUM_ENT) atomicAdd(&counts[d], 1);
    }
}

// ---------------------------------------------------------------------------
// Exclusive prefix sum over 30000 counts -> offsets[0..NUM_ENT], cursor copy.
// ---------------------------------------------------------------------------
__global__ __launch_bounds__(1024) void k_scan(const int* __restrict__ counts,
                                               int* __restrict__ offsets,
                                               int* __restrict__ cursor) {
    __shared__ int part[1024];
    int t = threadIdx.x;
    const int CH = (NUM_ENT + 1023) / 1024;     // 30
    int base = t * CH;
    int s = 0;
    for (int i = 0; i < CH; ++i) {
        int idx = base + i;
        if (idx < NUM_ENT) s += counts[idx];
    }
    part[t] = s;
    __syncthreads();
    for (int off = 1; off < 1024; off <<= 1) {
        int v = (t >= off) ? part[t - off] : 0;
        __syncthreads();
        part[t] += v;
        __syncthreads();
    }
    int run = (t == 0) ? 0 : part[t - 1];
    for (int i = 0; i < CH; ++i) {
        int idx = base + i;
        if (idx < NUM_ENT) {
            offsets[idx] = run;
            cursor[idx]  = run;
            run += counts[idx];
        }
    }
    if (t == 1023) offsets[NUM_ENT] = part[1023];
}

// ---------------------------------------------------------------------------
// Bucket edge ids by destination node.
// ---------------------------------------------------------------------------
__global__ void k_place(const int* __restrict__ edst, int* __restrict__ cursor,
                        int* __restrict__ sorted) {
    int e = blockIdx.x * blockDim.x + threadIdx.x;
    if (e < N_EDGES) {
        int d = edst[e];
        if (d < NUM_ENT) {
            int p = atomicAdd(&cursor[d], 1);
            sorted[p] = e;
        }
    }
}

// ---------------------------------------------------------------------------
// One wave per node. rgcn_weight staged in LDS (8 KB); edge loop unrolled x4
// with 4 independent accumulators. Writes agg (f32) + bf16 S row. No atomics.
// ---------------------------------------------------------------------------
__global__ void k_aggregate(const float* __restrict__ ent, const float* __restrict__ attr,
                            const float* __restrict__ w, const int* __restrict__ esrc,
                            const int* __restrict__ etype, const int* __restrict__ offsets,
                            const int* __restrict__ sorted, const float* __restrict__ norm,
                            float* __restrict__ agg, bf16* __restrict__ S) {
    __shared__ float wl[NUM_TYPES * HIDDEN];    // 8 KB
    for (int i = threadIdx.x; i < NUM_TYPES * HIDDEN; i += blockDim.x)
        wl[i] = w[i];
    __syncthreads();

    int n    = (blockIdx.x * blockDim.x + threadIdx.x) >> 6;
    int lane = threadIdx.x & 63;
    if (n >= NPAD) return;

    if (n >= NUM_ENT) {                         // S zero-pad rows
        if (lane < KPAD / 4) {
            bf16 z4[4] = {};
            *reinterpret_cast<uint2*>(S + (size_t)n * KPAD + lane * 4) =
                *reinterpret_cast<uint2*>(z4);
        }
        return;
    }

    int beg = offsets[n], end = offsets[n + 1];
    bool act = lane < 50;
    int  c   = lane * 4;

    float4 a0 = make_float4(0, 0, 0, 0), a1 = a0, a2 = a0, a3 = a0;
    int e = beg;
    for (; e + 4 <= end; e += 4) {
        int e0 = sorted[e + 0], e1 = sorted[e + 1], e2 = sorted[e + 2], e3 = sorted[e + 3];
        int s0 = esrc[e0], s1 = esrc[e1], s2 = esrc[e2], s3 = esrc[e3];
        int t0 = etype[e0], t1 = etype[e1], t2 = etype[e2], t3 = etype[e3];
        if (act) {
            const float* p0 = (s0 < NUM_ENT) ? ent + (size_t)s0 * HIDDEN : attr + (size_t)(s0 - NUM_ENT) * HIDDEN;
            const float* p1 = (s1 < NUM_ENT) ? ent + (size_t)s1 * HIDDEN : attr + (size_t)(s1 - NUM_ENT) * HIDDEN;
            const float* p2 = (s2 < NUM_ENT) ? ent + (size_t)s2 * HIDDEN : attr + (size_t)(s2 - NUM_ENT) * HIDDEN;
            const float* p3 = (s3 < NUM_ENT) ? ent + (size_t)s3 * HIDDEN : attr + (size_t)(s3 - NUM_ENT) * HIDDEN;
            float4 h0 = *reinterpret_cast<const float4*>(p0 + c);
            float4 h1 = *reinterpret_cast<const float4*>(p1 + c);
            float4 h2 = *reinterpret_cast<const float4*>(p2 + c);
            float4 h3 = *reinterpret_cast<const float4*>(p3 + c);
            float4 w0 = *reinterpret_cast<const float4*>(&wl[t0 * HIDDEN + c]);
            float4 w1 = *reinterpret_cast<const float4*>(&wl[t1 * HIDDEN + c]);
            float4 w2 = *reinterpret_cast<const float4*>(&wl[t2 * HIDDEN + c]);
            float4 w3 = *reinterpret_cast<const float4*>(&wl[t3 * HIDDEN + c]);
            a0.x += h0.x * w0.x; a0.y += h0.y * w0.y; a0.z += h0.z * w0.z; a0.w += h0.w * w0.w;
            a1.x += h1.x * w1.x; a1.y += h1.y * w1.y; a1.z += h1.z * w1.z; a1.w += h1.w * w1.w;
            a2.x += h2.x * w2.x; a2.y += h2.y * w2.y; a2.z += h2.z * w2.z; a2.w += h2.w * w2.w;
            a3.x += h3.x * w3.x; a3.y += h3.y * w3.y; a3.z += h3.z * w3.z; a3.w += h3.w * w3.w;
        }
    }
    for (; e < end; ++e) {
        int e0 = sorted[e];
        int s0 = esrc[e0];
        int t0 = etype[e0];
        if (act) {
            const float* p0 = (s0 < NUM_ENT) ? ent + (size_t)s0 * HIDDEN : attr + (size_t)(s0 - NUM_ENT) * HIDDEN;
            float4 h0 = *reinterpret_cast<const float4*>(p0 + c);
            float4 w0 = *reinterpret_cast<const float4*>(&wl[t0 * HIDDEN + c]);
            a0.x += h0.x * w0.x; a0.y += h0.y * w0.y; a0.z += h0.z * w0.z; a0.w += h0.w * w0.w;
        }
    }

    if (act) {
        float4 acc = make_float4(a0.x + a1.x + a2.x + a3.x,
                                 a0.y + a1.y + a2.y + a3.y,
                                 a0.z + a1.z + a2.z + a3.z,
                                 a0.w + a1.w + a2.w + a3.w);
        *reinterpret_cast<float4*>(agg + (size_t)n * HIDDEN + c) = acc;
        float nm = norm[n];
        float v0 = acc.x * nm, v1 = acc.y * nm, v2 = acc.z * nm, v3 = acc.w * nm;
        v0 = (v0 >= 0.f) ? v0 : RRELU_SLOPE * v0;
        v1 = (v1 >= 0.f) ? v1 : RRELU_SLOPE * v1;
        v2 = (v2 >= 0.f) ? v2 : RRELU_SLOPE * v2;
        v3 = (v3 >= 0.f) ? v3 : RRELU_SLOPE * v3;
        bf16 t4[4] = {__float2bfloat16(v0), __float2bfloat16(v1),
                      __float2bfloat16(v2), __float2bfloat16(v3)};
        *reinterpret_cast<uint2*>(S + (size_t)n * KPAD + lane * 4) =
            *reinterpret_cast<uint2*>(t4);
    } else if (lane < KPAD / 4) {               // K-pad 200..223 -> zero
        bf16 z4[4] = {};
        *reinterpret_cast<uint2*>(S + (size_t)n * KPAD + lane * 4) =
            *reinterpret_cast<uint2*>(z4);
    }
}

// ---------------------------------------------------------------------------
// Y[m][n] = relu( x[m] . dec_W[n] + dec_b[n] )  as bf16 padded to KPAD.
// ---------------------------------------------------------------------------
__global__ void k_build_Y(const float* __restrict__ agg, const float* __restrict__ norm,
                          const float* __restrict__ rel_emb, const float* __restrict__ time_emb,
                          const float* __restrict__ dec_W, const float* __restrict__ dec_b,
                          const int* __restrict__ batch, bf16* __restrict__ Y) {
    __shared__ float xs[16][405];               // stride 405: odd vs 32 banks, conflict-free
    int t = threadIdx.x;
    int blk = blockIdx.x;
    for (int idx = t; idx < 16 * XDIM; idx += 256) {
        int r = idx / XDIM, c = idx - r * XDIM;
        int m = blk * 16 + r;
        float v;
        if (c < HIDDEN) {
            int e = batch[m * 4 + 0];
            float h = agg[(size_t)e * HIDDEN + c] * norm[e];
            h = (h >= 0.f) ? h : RRELU_SLOPE * h;
            v = tanhf(h);
        } else if (c < 2 * HIDDEN) {
            int rl = batch[m * 4 + 1];
            v = rel_emb[(size_t)rl * HIDDEN + (c - HIDDEN)];
        } else {
            int traw = batch[m * 4 + 3];
            v = time_emb[traw / 24];
        }
        xs[r][c] = v;
    }
    __syncthreads();
    int r = t & 15;                             // batch row within block
    int g = t >> 4;                             // output-column group
    int m = blk * 16 + r;
    for (int n = g; n < KPAD; n += 16) {
        float acc = 0.f;
        if (n < HIDDEN) {
            acc = dec_b[n];
            const float* wrow = dec_W + (size_t)n * XDIM;
            for (int k = 0; k < XDIM; ++k)
                acc += xs[r][k] * wrow[k];
            acc = fmaxf(acc, 0.f);
        }
        Y[(size_t)m * KPAD + n] = __float2bfloat16(acc);
    }
}

// ---------------------------------------------------------------------------
// out[4096][30000] (f32) = Y(4096xK) . S^T(Kx30000), bf16 MFMA 16x16x32.
// LDS-staged: whole K extent of both tiles (2 x 128x224 bf16 = 114.7 KB LDS)
// staged once via XOR-swizzled ds_write_b128, ONE barrier, then 7 K-steps of
// pure ds_read_b128 + MFMA. XOR swizzle byte^=((row&7)<<4) makes the
// stride-448B 16-row fragment reads 2-way (free) instead of 2-bank serial.
// XCD-chunked 1D grid keeps each XCD's A+B panel (3.5 MB) L2-resident.
// ---------------------------------------------------------------------------
__global__ __launch_bounds__(256) void k_gemm(const bf16* __restrict__ Yb,
                                              const bf16* __restrict__ Sb,
                                              float* __restrict__ out) {
    __shared__ short As[128 * KPAD];            // 57,344 B
    __shared__ short Bs[128 * KPAD];            // 57,344 B

    int bid = blockIdx.x;                   // 0..7519 (= 235*32)
    int xcd = bid & 7;
    int t   = (bid >> 3) + xcd * 940;       // 7520/8 = 940, bijective
    int ytile = t & 31;                     // M tile (fast)
    int xtile = t >> 5;                     // N tile (slow, chunked per XCD)
    int tid = threadIdx.x;

    // ---- stage both tiles: thread t owns half-row (row = t>>1, half = t&1)
    {
        int row  = tid >> 1;
        int half = tid & 1;
        const ushort* gA = (const ushort*)Yb + (size_t)(ytile * 128 + row) * KPAD + half * 112;
        const ushort* gB = (const ushort*)Sb + (size_t)(xtile * 128 + row) * KPAD + half * 112;
        unsigned lb = row * 448 + half * 224;
        unsigned sw = (row & 7) << 4;
        char* Ab = (char*)As;
        char* Bb = (char*)Bs;
#pragma unroll
        for (int j = 0; j < 14; ++j) {
            uint4 va = *reinterpret_cast<const uint4*>(gA + j * 8);
            uint4 vb = *reinterpret_cast<const uint4*>(gB + j * 8);
            *reinterpret_cast<uint4*>(Ab + ((lb + j * 16) ^ sw)) = va;
            *reinterpret_cast<uint4*>(Bb + ((lb + j * 16) ^ sw)) = vb;
        }
    }
    __syncthreads();

    int wid  = tid >> 6;
    int lane = tid & 63;
    int wm = wid >> 1, wn = wid & 1;
    int rsel = lane & 15;
    int hi   = lane >> 4;
    unsigned swr = (rsel & 7) << 4;         // (row&7) == (rsel&7): row base ≡ 0 mod 8
    const char* Ab = (const char*)As;
    const char* Bb = (const char*)Bs;

    f32x4 acc[4][4] = {};
#pragma unroll
    for (int kt = 0; kt < 7; ++kt) {
        int kb = kt * 64 + hi * 16;         // byte offset of this lane's 8-bf16 chunk
        bf16x8 a[4], b[4];
#pragma unroll
        for (int i = 0; i < 4; ++i) {
            unsigned ra = (unsigned)(wm * 64 + i * 16 + rsel) * 448 + kb;
            a[i] = *reinterpret_cast<const bf16x8*>(Ab + (ra ^ swr));
        }
#pragma unroll
        for (int j = 0; j < 4; ++j) {
            unsigned rb = (unsigned)(wn * 64 + j * 16 + rsel) * 448 + kb;
            b[j] = *reinterpret_cast<const bf16x8*>(Bb + (rb ^ swr));
        }
#pragma unroll
        for (int i = 0; i < 4; ++i)
#pragma unroll
            for (int j = 0; j < 4; ++j)
                acc[i][j] = __builtin_amdgcn_mfma_f32_16x16x32_bf16(a[i], b[j], acc[i][j], 0, 0, 0);
    }

    int row0 = ytile * 128 + wm * 64;
    int col0 = xtile * 128 + wn * 64;
    int crow = (lane >> 4) * 4;             // C/D layout: col=lane&15, row=(lane>>4)*4+r
    int ccol = lane & 15;
#pragma unroll
    for (int i = 0; i < 4; ++i)
#pragma unroll
        for (int j = 0; j < 4; ++j) {
            int col = col0 + j * 16 + ccol;
            if (col >= NUM_ENT) continue;
#pragma unroll
            for (int r = 0; r < 4; ++r) {
                int row = row0 + i * 16 + crow + r;
                out[(size_t)row * NUM_ENT + col] = acc[i][j][r];
            }
        }
}

// ---------------------------------------------------------------------------
extern "C" void kernel_launch(void* const* d_in, const int* in_sizes, int n_in,
                              void* d_out, int out_size, void* d_ws, size_t ws_size,
                              hipStream_t stream) {
    const float* ent_emb  = (const float*)d_in[0];
    const float* attr_emb = (const float*)d_in[1];
    const float* rel_emb  = (const float*)d_in[2];
    const float* time_emb = (const float*)d_in[3];
    const float* rgcn_w   = (const float*)d_in[4];
    const float* dec_W    = (const float*)d_in[5];
    const float* dec_b    = (const float*)d_in[6];
    const float* norm     = (const float*)d_in[7];
    const int*   esrc     = (const int*)d_in[8];
    const int*   edst     = (const int*)d_in[9];
    const int*   etype    = (const int*)d_in[10];
    const int*   batch    = (const int*)d_in[11];

    char* ws = (char*)d_ws;
    float* agg    = (float*)ws;                         // 24,000,000 B
    bf16*  S      = (bf16*)(ws + 24000000);             // 13,475,840 B
    bf16*  Y      = (bf16*)(ws + 37475840);             //  1,835,008 B
    int*   counts = (int*)(ws + 39310848);              //   120,064 B (30001 ints)
    int*   offs   = (int*)(ws + 39430912);              //   120,064 B (30001 ints)
    int*   cursor = (int*)(ws + 39550976);              //   120,064 B (30000 ints)
    int*   sorted = (int*)(ws + 39671040);              // 2,400,000 B (600000 ints)

    k_zero_i<<<(NUM_ENT + 1 + 255) / 256, 256, 0, stream>>>(counts, NUM_ENT + 1);
    k_hist  <<<(N_EDGES + 255) / 256, 256, 0, stream>>>(edst, counts);
    k_scan  <<<1, 1024, 0, stream>>>(counts, offs, cursor);
    k_place <<<(N_EDGES + 255) / 256, 256, 0, stream>>>(edst, cursor, sorted);
    k_aggregate<<<NPAD * 64 / 256, 256, 0, stream>>>(ent_emb, attr_emb, rgcn_w, esrc, etype,
                                                     offs, sorted, norm, agg, S);
    k_build_Y<<<BATCH / 16, 256, 0, stream>>>(agg, norm, rel_emb, time_emb, dec_W, dec_b, batch, Y);

    k_gemm<<<7520, 256, 0, stream>>>(Y, S, (float*)d_out);
}

// Round 6
// 488.994 us; speedup vs baseline: 1.4325x; 1.4325x over previous
//
#include <hip/hip_runtime.h>
#include <hip/hip_bf16.h>

#define NUM_ENT   30000
#define NUM_ATTR  10000
#define NUM_TYPES 10
#define HIDDEN    200
#define KPAD      224      // HIDDEN padded to 7*32 for MFMA K-tiles (big GEMM K / dec N)
#define XP        416      // decoder K: 401 padded to 13*32
#define NPAD      30080    // NUM_ENT padded to 235*128
#define N_EDGES   600000
#define BATCH     4096
#define XDIM      401      // 2*HIDDEN + 1
#define RRELU_SLOPE 0.22916666666666666f

using bf16x8 = __attribute__((ext_vector_type(8))) short;
using f32x4  = __attribute__((ext_vector_type(4))) float;
typedef __hip_bfloat16 bf16;

// ---------------------------------------------------------------------------
__global__ void k_zero_i(int* __restrict__ p, int n) {
    int i = blockIdx.x * blockDim.x + threadIdx.x;
    if (i < n) p[i] = 0;
}

// ---------------------------------------------------------------------------
__global__ void k_hist(const int* __restrict__ edst, int* __restrict__ counts) {
    int e = blockIdx.x * blockDim.x + threadIdx.x;
    if (e < N_EDGES) {
        int d = edst[e];
        if (d < NUM_ENT) atomicAdd(&counts[d], 1);
    }
}

// ---------------------------------------------------------------------------
__global__ __launch_bounds__(1024) void k_scan(const int* __restrict__ counts,
                                               int* __restrict__ offsets,
                                               int* __restrict__ cursor) {
    __shared__ int part[1024];
    int t = threadIdx.x;
    const int CH = (NUM_ENT + 1023) / 1024;     // 30
    int base = t * CH;
    int s = 0;
    for (int i = 0; i < CH; ++i) {
        int idx = base + i;
        if (idx < NUM_ENT) s += counts[idx];
    }
    part[t] = s;
    __syncthreads();
    for (int off = 1; off < 1024; off <<= 1) {
        int v = (t >= off) ? part[t - off] : 0;
        __syncthreads();
        part[t] += v;
        __syncthreads();
    }
    int run = (t == 0) ? 0 : part[t - 1];
    for (int i = 0; i < CH; ++i) {
        int idx = base + i;
        if (idx < NUM_ENT) {
            offsets[idx] = run;
            cursor[idx]  = run;
            run += counts[idx];
        }
    }
    if (t == 1023) offsets[NUM_ENT] = part[1023];
}

// ---------------------------------------------------------------------------
__global__ void k_place(const int* __restrict__ edst, int* __restrict__ cursor,
                        int* __restrict__ sorted) {
    int e = blockIdx.x * blockDim.x + threadIdx.x;
    if (e < N_EDGES) {
        int d = edst[e];
        if (d < NUM_ENT) {
            int p = atomicAdd(&cursor[d], 1);
            sorted[p] = e;
        }
    }
}

// ---------------------------------------------------------------------------
// One wave per node; rgcn_weight in LDS; x4 unrolled gather loop; no atomics.
// Writes agg (f32) + bf16 S row (rrelu*norm, zero-padded).
// ---------------------------------------------------------------------------
__global__ void k_aggregate(const float* __restrict__ ent, const float* __restrict__ attr,
                            const float* __restrict__ w, const int* __restrict__ esrc,
                            const int* __restrict__ etype, const int* __restrict__ offsets,
                            const int* __restrict__ sorted, const float* __restrict__ norm,
                            float* __restrict__ agg, bf16* __restrict__ S) {
    __shared__ float wl[NUM_TYPES * HIDDEN];    // 8 KB
    for (int i = threadIdx.x; i < NUM_TYPES * HIDDEN; i += blockDim.x)
        wl[i] = w[i];
    __syncthreads();

    int n    = (blockIdx.x * blockDim.x + threadIdx.x) >> 6;
    int lane = threadIdx.x & 63;
    if (n >= NPAD) return;

    if (n >= NUM_ENT) {                         // S zero-pad rows
        if (lane < KPAD / 4) {
            bf16 z4[4] = {};
            *reinterpret_cast<uint2*>(S + (size_t)n * KPAD + lane * 4) =
                *reinterpret_cast<uint2*>(z4);
        }
        return;
    }

    int beg = offsets[n], end = offsets[n + 1];
    bool act = lane < 50;
    int  c   = lane * 4;

    float4 a0 = make_float4(0, 0, 0, 0), a1 = a0, a2 = a0, a3 = a0;
    int e = beg;
    for (; e + 4 <= end; e += 4) {
        int e0 = sorted[e + 0], e1 = sorted[e + 1], e2 = sorted[e + 2], e3 = sorted[e + 3];
        int s0 = esrc[e0], s1 = esrc[e1], s2 = esrc[e2], s3 = esrc[e3];
        int t0 = etype[e0], t1 = etype[e1], t2 = etype[e2], t3 = etype[e3];
        if (act) {
            const float* p0 = (s0 < NUM_ENT) ? ent + (size_t)s0 * HIDDEN : attr + (size_t)(s0 - NUM_ENT) * HIDDEN;
            const float* p1 = (s1 < NUM_ENT) ? ent + (size_t)s1 * HIDDEN : attr + (size_t)(s1 - NUM_ENT) * HIDDEN;
            const float* p2 = (s2 < NUM_ENT) ? ent + (size_t)s2 * HIDDEN : attr + (size_t)(s2 - NUM_ENT) * HIDDEN;
            const float* p3 = (s3 < NUM_ENT) ? ent + (size_t)s3 * HIDDEN : attr + (size_t)(s3 - NUM_ENT) * HIDDEN;
            float4 h0 = *reinterpret_cast<const float4*>(p0 + c);
            float4 h1 = *reinterpret_cast<const float4*>(p1 + c);
            float4 h2 = *reinterpret_cast<const float4*>(p2 + c);
            float4 h3 = *reinterpret_cast<const float4*>(p3 + c);
            float4 w0 = *reinterpret_cast<const float4*>(&wl[t0 * HIDDEN + c]);
            float4 w1 = *reinterpret_cast<const float4*>(&wl[t1 * HIDDEN + c]);
            float4 w2 = *reinterpret_cast<const float4*>(&wl[t2 * HIDDEN + c]);
            float4 w3 = *reinterpret_cast<const float4*>(&wl[t3 * HIDDEN + c]);
            a0.x += h0.x * w0.x; a0.y += h0.y * w0.y; a0.z += h0.z * w0.z; a0.w += h0.w * w0.w;
            a1.x += h1.x * w1.x; a1.y += h1.y * w1.y; a1.z += h1.z * w1.z; a1.w += h1.w * w1.w;
            a2.x += h2.x * w2.x; a2.y += h2.y * w2.y; a2.z += h2.z * w2.z; a2.w += h2.w * w2.w;
            a3.x += h3.x * w3.x; a3.y += h3.y * w3.y; a3.z += h3.z * w3.z; a3.w += h3.w * w3.w;
        }
    }
    for (; e < end; ++e) {
        int e0 = sorted[e];
        int s0 = esrc[e0];
        int t0 = etype[e0];
        if (act) {
            const float* p0 = (s0 < NUM_ENT) ? ent + (size_t)s0 * HIDDEN : attr + (size_t)(s0 - NUM_ENT) * HIDDEN;
            float4 h0 = *reinterpret_cast<const float4*>(p0 + c);
            float4 w0 = *reinterpret_cast<const float4*>(&wl[t0 * HIDDEN + c]);
            a0.x += h0.x * w0.x; a0.y += h0.y * w0.y; a0.z += h0.z * w0.z; a0.w += h0.w * w0.w;
        }
    }

    if (act) {
        float4 acc = make_float4(a0.x + a1.x + a2.x + a3.x,
                                 a0.y + a1.y + a2.y + a3.y,
                                 a0.z + a1.z + a2.z + a3.z,
                                 a0.w + a1.w + a2.w + a3.w);
        *reinterpret_cast<float4*>(agg + (size_t)n * HIDDEN + c) = acc;
        float nm = norm[n];
        float v0 = acc.x * nm, v1 = acc.y * nm, v2 = acc.z * nm, v3 = acc.w * nm;
        v0 = (v0 >= 0.f) ? v0 : RRELU_SLOPE * v0;
        v1 = (v1 >= 0.f) ? v1 : RRELU_SLOPE * v1;
        v2 = (v2 >= 0.f) ? v2 : RRELU_SLOPE * v2;
        v3 = (v3 >= 0.f) ? v3 : RRELU_SLOPE * v3;
        bf16 t4[4] = {__float2bfloat16(v0), __float2bfloat16(v1),
                      __float2bfloat16(v2), __float2bfloat16(v3)};
        *reinterpret_cast<uint2*>(S + (size_t)n * KPAD + lane * 4) =
            *reinterpret_cast<uint2*>(t4);
    } else if (lane < KPAD / 4) {
        bf16 z4[4] = {};
        *reinterpret_cast<uint2*>(S + (size_t)n * KPAD + lane * 4) =
            *reinterpret_cast<uint2*>(z4);
    }
}

// ---------------------------------------------------------------------------
// X[m][c] (bf16, [4096][416]): [tanh(rrelu(agg[ent]*norm)), rel_emb, time, 0pad]
// One block per batch row; fully parallel, coalesced agg row read.
// ---------------------------------------------------------------------------
__global__ void k_build_X(const float* __restrict__ agg, const float* __restrict__ norm,
                          const float* __restrict__ rel_emb, const float* __restrict__ time_emb,
                          const int* __restrict__ batch, bf16* __restrict__ X) {
    int m = blockIdx.x;
    int e  = batch[m * 4 + 0];
    int rl = batch[m * 4 + 1];
    int tr = batch[m * 4 + 3];
    float nm = norm[e];
    float tv = time_emb[tr / 24];
    for (int c = threadIdx.x; c < XP; c += 256) {
        float v;
        if (c < HIDDEN) {
            float h = agg[(size_t)e * HIDDEN + c] * nm;
            h = (h >= 0.f) ? h : RRELU_SLOPE * h;
            v = tanhf(h);
        } else if (c < 2 * HIDDEN) {
            v = rel_emb[(size_t)rl * HIDDEN + (c - HIDDEN)];
        } else if (c == 2 * HIDDEN) {
            v = tv;
        } else {
            v = 0.f;
        }
        X[(size_t)m * XP + c] = __float2bfloat16(v);
    }
}

// ---------------------------------------------------------------------------
// Wb[n][k] (bf16, [224][416]) = dec_W[n][k] for n<200,k<401 else 0.
// Rows 200..223 are zero so dec-gemm produces exactly 0 in Y's K-pad cols.
// ---------------------------------------------------------------------------
__global__ void k_build_Wb(const float* __restrict__ dec_W, bf16* __restrict__ Wb) {
    int n = blockIdx.x;
    for (int c = threadIdx.x; c < XP; c += 256) {
        float v = (n < HIDDEN && c < XDIM) ? dec_W[(size_t)n * XDIM + c] : 0.f;
        Wb[(size_t)n * XP + c] = __float2bfloat16(v);
    }
}

// ---------------------------------------------------------------------------
// Y[4096][224] bf16 = relu( X(4096x416) . Wb^T(416x224) + b ), MFMA 16x16x32.
// 32 blocks x 4 waves; wave w: rows blk*128+w*32 (2 row-frags) x all 14 col-frags.
// ---------------------------------------------------------------------------
__global__ __launch_bounds__(256) void k_dec_gemm(const bf16* __restrict__ Xb,
                                                  const bf16* __restrict__ Wbb,
                                                  const float* __restrict__ dec_b,
                                                  bf16* __restrict__ Y) {
    int wid  = threadIdx.x >> 6;
    int lane = threadIdx.x & 63;
    int row0 = blockIdx.x * 128 + wid * 32;
    int rsel = lane & 15;
    int koff = (lane >> 4) * 8;

    const short* Xp = reinterpret_cast<const short*>(Xb);
    const short* Wp = reinterpret_cast<const short*>(Wbb);

    f32x4 acc[2][14] = {};
#pragma unroll
    for (int kt = 0; kt < 13; ++kt) {
        int kbase = kt * 32 + koff;
        bf16x8 a[2];
#pragma unroll
        for (int i = 0; i < 2; ++i)
            a[i] = *reinterpret_cast<const bf16x8*>(Xp + (size_t)(row0 + i * 16 + rsel) * XP + kbase);
#pragma unroll
        for (int j = 0; j < 14; ++j) {
            bf16x8 b = *reinterpret_cast<const bf16x8*>(Wp + (size_t)(j * 16 + rsel) * XP + kbase);
#pragma unroll
            for (int i = 0; i < 2; ++i)
                acc[i][j] = __builtin_amdgcn_mfma_f32_16x16x32_bf16(a[i], b, acc[i][j], 0, 0, 0);
        }
    }

    int crow = (lane >> 4) * 4;     // C/D: col=lane&15, row=(lane>>4)*4+r
    int ccol = lane & 15;
#pragma unroll
    for (int j = 0; j < 14; ++j) {
        int col = j * 16 + ccol;
        float bias = (col < HIDDEN) ? dec_b[col] : 0.f;
#pragma unroll
        for (int i = 0; i < 2; ++i)
#pragma unroll
            for (int r = 0; r < 4; ++r) {
                int row = row0 + i * 16 + crow + r;
                float v = fmaxf(acc[i][j][r] + bias, 0.f);
                Y[(size_t)row * KPAD + col] = __float2bfloat16(v);
            }
    }
}

// ---------------------------------------------------------------------------
// out[4096][30000] (f32) = Y(4096x224) . S^T(224x30000), bf16 MFMA 16x16x32.
// R4 L2-direct version with XCD-chunked swizzle (R5 LDS variant regressed).
// ---------------------------------------------------------------------------
__global__ __launch_bounds__(256) void k_gemm(const bf16* __restrict__ Yb,
                                              const bf16* __restrict__ Sb,
                                              float* __restrict__ out) {
    int bid = blockIdx.x;                   // 0..7519 (= 235*32)
    int xcd = bid & 7;
    int t   = (bid >> 3) + xcd * 940;       // 7520/8 = 940, bijective
    int ytile = t & 31;                     // M tile (fast)
    int xtile = t >> 5;                     // N tile (slow, chunked per XCD)

    int wid  = threadIdx.x >> 6;
    int lane = threadIdx.x & 63;
    int wm = wid >> 1, wn = wid & 1;
    int row0 = ytile * 128 + wm * 64;
    int col0 = xtile * 128 + wn * 64;
    int rsel = lane & 15;
    int koff = (lane >> 4) * 8;

    const short* Yp = reinterpret_cast<const short*>(Yb);
    const short* Sp = reinterpret_cast<const short*>(Sb);

    f32x4 acc[4][4] = {};
#pragma unroll
    for (int kt = 0; kt < 7; ++kt) {
        int kbase = kt * 32 + koff;
        bf16x8 a[4], b[4];
#pragma unroll
        for (int i = 0; i < 4; ++i)
            a[i] = *reinterpret_cast<const bf16x8*>(Yp + (size_t)(row0 + i * 16 + rsel) * KPAD + kbase);
#pragma unroll
        for (int j = 0; j < 4; ++j)
            b[j] = *reinterpret_cast<const bf16x8*>(Sp + (size_t)(col0 + j * 16 + rsel) * KPAD + kbase);
#pragma unroll
        for (int i = 0; i < 4; ++i)
#pragma unroll
            for (int j = 0; j < 4; ++j)
                acc[i][j] = __builtin_amdgcn_mfma_f32_16x16x32_bf16(a[i], b[j], acc[i][j], 0, 0, 0);
    }

    int crow = (lane >> 4) * 4;     // C/D layout: col=lane&15, row=(lane>>4)*4+r
    int ccol = lane & 15;
#pragma unroll
    for (int i = 0; i < 4; ++i)
#pragma unroll
        for (int j = 0; j < 4; ++j) {
            int col = col0 + j * 16 + ccol;
            if (col >= NUM_ENT) continue;
#pragma unroll
            for (int r = 0; r < 4; ++r) {
                int row = row0 + i * 16 + crow + r;
                out[(size_t)row * NUM_ENT + col] = acc[i][j][r];
            }
        }
}

// ---------------------------------------------------------------------------
extern "C" void kernel_launch(void* const* d_in, const int* in_sizes, int n_in,
                              void* d_out, int out_size, void* d_ws, size_t ws_size,
                              hipStream_t stream) {
    const float* ent_emb  = (const float*)d_in[0];
    const float* attr_emb = (const float*)d_in[1];
    const float* rel_emb  = (const float*)d_in[2];
    const float* time_emb = (const float*)d_in[3];
    const float* rgcn_w   = (const float*)d_in[4];
    const float* dec_W    = (const float*)d_in[5];
    const float* dec_b    = (const float*)d_in[6];
    const float* norm     = (const float*)d_in[7];
    const int*   esrc     = (const int*)d_in[8];
    const int*   edst     = (const int*)d_in[9];
    const int*   etype    = (const int*)d_in[10];
    const int*   batch    = (const int*)d_in[11];

    char* ws = (char*)d_ws;
    float* agg    = (float*)ws;                         // 24,000,000 B
    bf16*  S      = (bf16*)(ws + 24000000);             // 13,475,840 B
    bf16*  Y      = (bf16*)(ws + 37475840);             //  1,835,008 B
    int*   counts = (int*)(ws + 39310848);              //   120,064 B
    int*   offs   = (int*)(ws + 39430912);              //   120,064 B
    int*   cursor = (int*)(ws + 39550976);              //   120,064 B
    int*   sorted = (int*)(ws + 39671040);              // 2,400,000 B
    bf16*  X      = (bf16*)(ws + 42071040);             // 3,407,872 B (4096x416)
    bf16*  Wb     = (bf16*)(ws + 45478912);             //   186,368 B (224x416)

    k_zero_i<<<(NUM_ENT + 1 + 255) / 256, 256, 0, stream>>>(counts, NUM_ENT + 1);
    k_hist  <<<(N_EDGES + 255) / 256, 256, 0, stream>>>(edst, counts);
    k_scan  <<<1, 1024, 0, stream>>>(counts, offs, cursor);
    k_place <<<(N_EDGES + 255) / 256, 256, 0, stream>>>(edst, cursor, sorted);
    k_aggregate<<<NPAD * 64 / 256, 256, 0, stream>>>(ent_emb, attr_emb, rgcn_w, esrc, etype,
                                                     offs, sorted, norm, agg, S);
    k_build_X<<<BATCH, 256, 0, stream>>>(agg, norm, rel_emb, time_emb, batch, X);
    k_build_Wb<<<KPAD, 256, 0, stream>>>(dec_W, Wb);
    k_dec_gemm<<<BATCH / 128, 256, 0, stream>>>(X, Wb, dec_b, Y);

    k_gemm<<<7520, 256, 0, stream>>>(Y, S, (float*)d_out);
}

// Round 7
// 395.174 us; speedup vs baseline: 1.7726x; 1.2374x over previous
//
#include <hip/hip_runtime.h>
#include <hip/hip_bf16.h>

#define NUM_ENT   30000
#define NUM_ATTR  10000
#define NUM_NODES 40000
#define NUM_TYPES 10
#define HIDDEN    200
#define KPAD      224      // HIDDEN padded for MFMA K (big GEMM) / N (decoder)
#define XP        416      // decoder K: 401 padded to 13*32
#define NPAD      30080    // NUM_ENT padded to 235*128
#define N_EDGES   600000
#define BATCH     4096
#define XDIM      401      // 2*HIDDEN + 1
#define RRELU_SLOPE 0.22916666666666666f

using bf16x8 = __attribute__((ext_vector_type(8))) short;
using f32x4  = __attribute__((ext_vector_type(4))) float;
typedef __hip_bfloat16 bf16;

__device__ inline float bf2f(ushort u) { return __uint_as_float((unsigned)u << 16); }

// ---------------------------------------------------------------------------
// Convert ent||attr (f32) to concatenated bf16 h0b[40000][200].
// ---------------------------------------------------------------------------
__global__ void k_cvt(const float* __restrict__ ent, const float* __restrict__ attr,
                      ushort* __restrict__ h0b) {
    int i4 = blockIdx.x * blockDim.x + threadIdx.x;      // float4 index
    if (i4 >= NUM_NODES * HIDDEN / 4) return;
    int base = i4 * 4;
    const float* src = (base < NUM_ENT * HIDDEN) ? ent + base
                                                 : attr + (base - NUM_ENT * HIDDEN);
    float4 v = *reinterpret_cast<const float4*>(src);
    ushort4 o;
    o.x = __bfloat16_as_ushort(__float2bfloat16(v.x));
    o.y = __bfloat16_as_ushort(__float2bfloat16(v.y));
    o.z = __bfloat16_as_ushort(__float2bfloat16(v.z));
    o.w = __bfloat16_as_ushort(__float2bfloat16(v.w));
    *reinterpret_cast<ushort4*>(h0b + base) = o;
}

// ---------------------------------------------------------------------------
// caps from norm (cap = round(1/norm) >= count; deg=0 -> 1, never filled),
// exclusive scan -> offsets + cursor init. Single block, 1024 threads.
// ---------------------------------------------------------------------------
__global__ __launch_bounds__(1024) void k_prep(const float* __restrict__ norm,
                                               int* __restrict__ offsets,
                                               int* __restrict__ cursor) {
    __shared__ int part[1024];
    int t = threadIdx.x;
    const int CH = (NUM_ENT + 1023) / 1024;     // 30
    int base = t * CH;
    int caps[CH];
    int s = 0;
    for (int i = 0; i < CH; ++i) {
        int idx = base + i;
        int c = 0;
        if (idx < NUM_ENT) c = (int)(1.0f / norm[idx] + 0.5f);
        caps[i] = c;
        s += c;
    }
    part[t] = s;
    __syncthreads();
    for (int off = 1; off < 1024; off <<= 1) {
        int v = (t >= off) ? part[t - off] : 0;
        __syncthreads();
        part[t] += v;
        __syncthreads();
    }
    int run = (t == 0) ? 0 : part[t - 1];
    for (int i = 0; i < CH; ++i) {
        int idx = base + i;
        if (idx < NUM_ENT) {
            offsets[idx] = run;
            cursor[idx]  = run;
            run += caps[i];
        }
    }
}

// ---------------------------------------------------------------------------
// Bucket edges by destination; store packed (src<<4 | type).
// ---------------------------------------------------------------------------
__global__ void k_place(const int* __restrict__ edst, const int* __restrict__ esrc,
                        const int* __restrict__ etype, int* __restrict__ cursor,
                        int* __restrict__ sorted) {
    int e = blockIdx.x * blockDim.x + threadIdx.x;
    if (e < N_EDGES) {
        int d = edst[e];
        if (d < NUM_ENT) {
            int p = atomicAdd(&cursor[d], 1);
            sorted[p] = (esrc[e] << 4) | etype[e];
        }
    }
}

// ---------------------------------------------------------------------------
// One wave per node: gather bf16 h0b rows, multiply by LDS-staged rgcn_weight,
// f32-accumulate, write bf16 S row (rrelu*norm, zero-padded). No atomics.
// Iterates offs[n]..cursor[n] (cursor = final fill position after k_place).
// ---------------------------------------------------------------------------
__global__ void k_aggregate(const ushort* __restrict__ h0b, const float* __restrict__ w,
                            const int* __restrict__ offsets, const int* __restrict__ cursor,
                            const int* __restrict__ sorted, const float* __restrict__ norm,
                            bf16* __restrict__ S) {
    __shared__ float wl[NUM_TYPES * HIDDEN];    // 8 KB
    for (int i = threadIdx.x; i < NUM_TYPES * HIDDEN; i += blockDim.x)
        wl[i] = w[i];
    __syncthreads();

    int n    = (blockIdx.x * blockDim.x + threadIdx.x) >> 6;
    int lane = threadIdx.x & 63;
    if (n >= NPAD) return;

    if (n >= NUM_ENT) {                         // S zero-pad rows
        if (lane < KPAD / 4) {
            bf16 z4[4] = {};
            *reinterpret_cast<uint2*>(S + (size_t)n * KPAD + lane * 4) =
                *reinterpret_cast<uint2*>(z4);
        }
        return;
    }

    int beg = offsets[n], end = cursor[n];
    bool act = lane < 50;
    int  c   = lane * 4;

    float4 a0 = make_float4(0, 0, 0, 0), a1 = a0, a2 = a0, a3 = a0;
    int e = beg;
    for (; e + 4 <= end; e += 4) {
        int r0 = sorted[e + 0], r1 = sorted[e + 1], r2 = sorted[e + 2], r3 = sorted[e + 3];
        if (act) {
            ushort4 h0 = *reinterpret_cast<const ushort4*>(h0b + (size_t)(r0 >> 4) * HIDDEN + c);
            ushort4 h1 = *reinterpret_cast<const ushort4*>(h0b + (size_t)(r1 >> 4) * HIDDEN + c);
            ushort4 h2 = *reinterpret_cast<const ushort4*>(h0b + (size_t)(r2 >> 4) * HIDDEN + c);
            ushort4 h3 = *reinterpret_cast<const ushort4*>(h0b + (size_t)(r3 >> 4) * HIDDEN + c);
            const float* w0 = &wl[(r0 & 15) * HIDDEN + c];
            const float* w1 = &wl[(r1 & 15) * HIDDEN + c];
            const float* w2 = &wl[(r2 & 15) * HIDDEN + c];
            const float* w3 = &wl[(r3 & 15) * HIDDEN + c];
            a0.x += bf2f(h0.x) * w0[0]; a0.y += bf2f(h0.y) * w0[1];
            a0.z += bf2f(h0.z) * w0[2]; a0.w += bf2f(h0.w) * w0[3];
            a1.x += bf2f(h1.x) * w1[0]; a1.y += bf2f(h1.y) * w1[1];
            a1.z += bf2f(h1.z) * w1[2]; a1.w += bf2f(h1.w) * w1[3];
            a2.x += bf2f(h2.x) * w2[0]; a2.y += bf2f(h2.y) * w2[1];
            a2.z += bf2f(h2.z) * w2[2]; a2.w += bf2f(h2.w) * w2[3];
            a3.x += bf2f(h3.x) * w3[0]; a3.y += bf2f(h3.y) * w3[1];
            a3.z += bf2f(h3.z) * w3[2]; a3.w += bf2f(h3.w) * w3[3];
        }
    }
    for (; e < end; ++e) {
        int r0 = sorted[e];
        if (act) {
            ushort4 h0 = *reinterpret_cast<const ushort4*>(h0b + (size_t)(r0 >> 4) * HIDDEN + c);
            const float* w0 = &wl[(r0 & 15) * HIDDEN + c];
            a0.x += bf2f(h0.x) * w0[0]; a0.y += bf2f(h0.y) * w0[1];
            a0.z += bf2f(h0.z) * w0[2]; a0.w += bf2f(h0.w) * w0[3];
        }
    }

    if (act) {
        float nm = norm[n];
        float v0 = (a0.x + a1.x + a2.x + a3.x) * nm;
        float v1 = (a0.y + a1.y + a2.y + a3.y) * nm;
        float v2 = (a0.z + a1.z + a2.z + a3.z) * nm;
        float v3 = (a0.w + a1.w + a2.w + a3.w) * nm;
        v0 = (v0 >= 0.f) ? v0 : RRELU_SLOPE * v0;
        v1 = (v1 >= 0.f) ? v1 : RRELU_SLOPE * v1;
        v2 = (v2 >= 0.f) ? v2 : RRELU_SLOPE * v2;
        v3 = (v3 >= 0.f) ? v3 : RRELU_SLOPE * v3;
        bf16 t4[4] = {__float2bfloat16(v0), __float2bfloat16(v1),
                      __float2bfloat16(v2), __float2bfloat16(v3)};
        *reinterpret_cast<uint2*>(S + (size_t)n * KPAD + lane * 4) =
            *reinterpret_cast<uint2*>(t4);
    } else if (lane < KPAD / 4) {               // K-pad 200..223 -> zero
        bf16 z4[4] = {};
        *reinterpret_cast<uint2*>(S + (size_t)n * KPAD + lane * 4) =
            *reinterpret_cast<uint2*>(z4);
    }
}

// ---------------------------------------------------------------------------
// Fused: blocks [0,BATCH) build X rows; blocks [BATCH, BATCH+KPAD) build Wb.
// X[m][c] = [tanh(S[ent]), rel_emb, time, 0pad]  (bf16, [4096][416])
// Wb[n][k] = dec_W zero-padded to [224][416].
// ---------------------------------------------------------------------------
__global__ void k_build_XW(const bf16* __restrict__ S, const float* __restrict__ rel_emb,
                           const float* __restrict__ time_emb, const float* __restrict__ dec_W,
                           const int* __restrict__ batch, bf16* __restrict__ X,
                           bf16* __restrict__ Wb) {
    int b = blockIdx.x;
    if (b < BATCH) {
        int m = b;
        int e  = batch[m * 4 + 0];
        int rl = batch[m * 4 + 1];
        int tr = batch[m * 4 + 3];
        float tv = time_emb[tr / 24];
        for (int c = threadIdx.x; c < XP; c += 256) {
            float v;
            if (c < HIDDEN) {
                v = tanhf(__bfloat162float(S[(size_t)e * KPAD + c]));
            } else if (c < 2 * HIDDEN) {
                v = rel_emb[(size_t)rl * HIDDEN + (c - HIDDEN)];
            } else if (c == 2 * HIDDEN) {
                v = tv;
            } else {
                v = 0.f;
            }
            X[(size_t)m * XP + c] = __float2bfloat16(v);
        }
    } else {
        int n = b - BATCH;
        for (int c = threadIdx.x; c < XP; c += 256) {
            float v = (n < HIDDEN && c < XDIM) ? dec_W[(size_t)n * XDIM + c] : 0.f;
            Wb[(size_t)n * XP + c] = __float2bfloat16(v);
        }
    }
}

// ---------------------------------------------------------------------------
// Y[4096][224] bf16 = relu( X(4096x416) . Wb^T(416x224) + b ), MFMA 16x16x32.
// 64 blocks x 4 waves; wave = 16 rows x all 14 col-frags (256 waves total).
// ---------------------------------------------------------------------------
__global__ __launch_bounds__(256) void k_dec_gemm(const bf16* __restrict__ Xb,
                                                  const bf16* __restrict__ Wbb,
                                                  const float* __restrict__ dec_b,
                                                  bf16* __restrict__ Y) {
    int wid  = threadIdx.x >> 6;
    int lane = threadIdx.x & 63;
    int row0 = blockIdx.x * 64 + wid * 16;
    int rsel = lane & 15;
    int koff = (lane >> 4) * 8;

    const short* Xp = reinterpret_cast<const short*>(Xb);
    const short* Wp = reinterpret_cast<const short*>(Wbb);

    f32x4 acc[14] = {};
#pragma unroll
    for (int kt = 0; kt < 13; ++kt) {
        int kbase = kt * 32 + koff;
        bf16x8 a = *reinterpret_cast<const bf16x8*>(Xp + (size_t)(row0 + rsel) * XP + kbase);
#pragma unroll
        for (int j = 0; j < 14; ++j) {
            bf16x8 b = *reinterpret_cast<const bf16x8*>(Wp + (size_t)(j * 16 + rsel) * XP + kbase);
            acc[j] = __builtin_amdgcn_mfma_f32_16x16x32_bf16(a, b, acc[j], 0, 0, 0);
        }
    }

    int crow = (lane >> 4) * 4;     // C/D: col=lane&15, row=(lane>>4)*4+r
    int ccol = lane & 15;
#pragma unroll
    for (int j = 0; j < 14; ++j) {
        int col = j * 16 + ccol;
        float bias = (col < HIDDEN) ? dec_b[col] : 0.f;
#pragma unroll
        for (int r = 0; r < 4; ++r) {
            int row = row0 + crow + r;
            float v = fmaxf(acc[j][r] + bias, 0.f);
            Y[(size_t)row * KPAD + col] = __float2bfloat16(v);
        }
    }
}

// ---------------------------------------------------------------------------
// out[4096][30000] (f32) = Y(4096x224) . S^T(224x30000), bf16 MFMA 16x16x32.
// L2-direct fragments, XCD-chunked block swizzle.
// ---------------------------------------------------------------------------
__global__ __launch_bounds__(256) void k_gemm(const bf16* __restrict__ Yb,
                                              const bf16* __restrict__ Sb,
                                              float* __restrict__ out) {
    int bid = blockIdx.x;                   // 0..7519 (= 235*32)
    int xcd = bid & 7;
    int t   = (bid >> 3) + xcd * 940;       // 7520/8 = 940, bijective
    int ytile = t & 31;                     // M tile (fast)
    int xtile = t >> 5;                     // N tile (slow, chunked per XCD)

    int wid  = threadIdx.x >> 6;
    int lane = threadIdx.x & 63;
    int wm = wid >> 1, wn = wid & 1;
    int row0 = ytile * 128 + wm * 64;
    int col0 = xtile * 128 + wn * 64;
    int rsel = lane & 15;
    int koff = (lane >> 4) * 8;

    const short* Yp = reinterpret_cast<const short*>(Yb);
    const short* Sp = reinterpret_cast<const short*>(Sb);

    f32x4 acc[4][4] = {};
#pragma unroll
    for (int kt = 0; kt < 7; ++kt) {
        int kbase = kt * 32 + koff;
        bf16x8 a[4], b[4];
#pragma unroll
        for (int i = 0; i < 4; ++i)
            a[i] = *reinterpret_cast<const bf16x8*>(Yp + (size_t)(row0 + i * 16 + rsel) * KPAD + kbase);
#pragma unroll
        for (int j = 0; j < 4; ++j)
            b[j] = *reinterpret_cast<const bf16x8*>(Sp + (size_t)(col0 + j * 16 + rsel) * KPAD + kbase);
#pragma unroll
        for (int i = 0; i < 4; ++i)
#pragma unroll
            for (int j = 0; j < 4; ++j)
                acc[i][j] = __builtin_amdgcn_mfma_f32_16x16x32_bf16(a[i], b[j], acc[i][j], 0, 0, 0);
    }

    int crow = (lane >> 4) * 4;     // C/D layout: col=lane&15, row=(lane>>4)*4+r
    int ccol = lane & 15;
#pragma unroll
    for (int i = 0; i < 4; ++i)
#pragma unroll
        for (int j = 0; j < 4; ++j) {
            int col = col0 + j * 16 + ccol;
            if (col >= NUM_ENT) continue;
#pragma unroll
            for (int r = 0; r < 4; ++r) {
                int row = row0 + i * 16 + crow + r;
                out[(size_t)row * NUM_ENT + col] = acc[i][j][r];
            }
        }
}

// ---------------------------------------------------------------------------
extern "C" void kernel_launch(void* const* d_in, const int* in_sizes, int n_in,
                              void* d_out, int out_size, void* d_ws, size_t ws_size,
                              hipStream_t stream) {
    const float* ent_emb  = (const float*)d_in[0];
    const float* attr_emb = (const float*)d_in[1];
    const float* rel_emb  = (const float*)d_in[2];
    const float* time_emb = (const float*)d_in[3];
    const float* rgcn_w   = (const float*)d_in[4];
    const float* dec_W    = (const float*)d_in[5];
    const float* dec_b    = (const float*)d_in[6];
    const float* norm     = (const float*)d_in[7];
    const int*   esrc     = (const int*)d_in[8];
    const int*   edst     = (const int*)d_in[9];
    const int*   etype    = (const int*)d_in[10];
    const int*   batch    = (const int*)d_in[11];

    char* ws = (char*)d_ws;
    bf16*   S      = (bf16*)ws;                           // 13,475,840 B
    bf16*   Y      = (bf16*)(ws + 13475840);              //  1,835,008 B
    int*    offs   = (int*)(ws + 15310848);               //    120,064 B
    int*    cursor = (int*)(ws + 15430912);               //    120,064 B
    int*    sorted = (int*)(ws + 15550976);               //  2,520,000 B (630000 recs)
    bf16*   X      = (bf16*)(ws + 18070976);              //  3,407,872 B (4096x416)
    bf16*   Wb     = (bf16*)(ws + 21478848);              //    186,368 B (224x416)
    ushort* h0b    = (ushort*)(ws + 21665216);            // 16,000,000 B (40000x200)

    k_cvt  <<<(NUM_NODES * HIDDEN / 4 + 255) / 256, 256, 0, stream>>>(ent_emb, attr_emb, h0b);
    k_prep <<<1, 1024, 0, stream>>>(norm, offs, cursor);
    k_place<<<(N_EDGES + 255) / 256, 256, 0, stream>>>(edst, esrc, etype, cursor, sorted);
    k_aggregate<<<NPAD * 64 / 256, 256, 0, stream>>>(h0b, rgcn_w, offs, cursor, sorted, norm, S);
    k_build_XW<<<BATCH + KPAD, 256, 0, stream>>>(S, rel_emb, time_emb, dec_W, batch, X, Wb);
    k_dec_gemm<<<BATCH / 64, 256, 0, stream>>>(X, Wb, dec_b, Y);
    k_gemm<<<7520, 256, 0, stream>>>(Y, S, (float*)d_out);
}